// Round 2
// baseline (1882.155 us; speedup 1.0000x reference)
//
#include <hip/hip_runtime.h>
#include <hip/hip_bf16.h>

#define T_LEN 1024
#define BATCH 32
#define HIDN  256
#define VOCAB 5000
#define MROWS (BATCH * T_LEN)                    // 32768
#define OUT_ELEMS ((size_t)MROWS * VOCAB)        // 163,840,000

typedef __bf16 bf16x8 __attribute__((ext_vector_type(8)));
typedef float  f32x4  __attribute__((ext_vector_type(4)));

// Verified gfx950 layouts (learn_hip m89/m120):
//   A-frag: lane holds A[m=lane&15][k=(lane>>4)*8+j]
//   B-frag: lane holds B[k=(lane>>4)*8+j][n=lane&15]
//   C/D   : lane,reg -> row m=(lane>>4)*4+reg, col n=lane&15
__device__ __forceinline__ f32x4 mfma16(bf16x8 a, bf16x8 b, f32x4 c) {
    return __builtin_amdgcn_mfma_f32_16x16x32_bf16(a, b, c, 0, 0, 0);
}

// 8 consecutive fp32 -> bf16x8 (two aligned 16B loads + cvt)
__device__ __forceinline__ bf16x8 cvt8(const float* p) {
    f32x4 f0 = *(const f32x4*)p;
    f32x4 f1 = *(const f32x4*)(p + 4);
    bf16x8 v;
    v[0] = (__bf16)f0[0]; v[1] = (__bf16)f0[1]; v[2] = (__bf16)f0[2]; v[3] = (__bf16)f0[3];
    v[4] = (__bf16)f1[0]; v[5] = (__bf16)f1[1]; v[6] = (__bf16)f1[2]; v[7] = (__bf16)f1[3];
    return v;
}

__device__ __forceinline__ float tanh_fast(float x) {
    float ax = __builtin_fabsf(x);
    if (__builtin_expect(ax > 0.55f, 0)) return tanhf(x);  // |z| ~ 0.025 here; rare
    float x2 = x * x;
    float q = fmaf(x2, 0.021869488f, -0.053968254f);
    q = fmaf(x2, q, 0.13333334f);
    q = fmaf(x2, q, -0.33333334f);
    return fmaf(x * x2, q, x);
}

// padding_idx=0 (idempotent; harness restores d_in each launch)
__global__ void zero_emb_row0(float* emb) {
    int i = threadIdx.x;
    if (i < HIDN) emb[i] = 0.0f;
}

// C[m][n] = sum_k A[m][k]*W[n][k] + bias[n];  A fp32-gathered (pre) or bf16 (decode).
// 128x128 tile, BK=32, 4 waves of 64x64. LDS rows padded to 40 elems.
template <bool AFP32>
__global__ __launch_bounds__(256, 2) void gemm_bias(
    const void* __restrict__ Abase, const int* __restrict__ idx,
    const float* __restrict__ W, int wstride,
    const float* __restrict__ bias,
    float* __restrict__ outp, int N, int ostride)
{
    __shared__ __align__(16) __bf16 At[128 * 40];
    __shared__ __align__(16) __bf16 Bt[128 * 40];
    const int tid  = threadIdx.x;
    const int lane = tid & 63;
    const int wv   = tid >> 6;
    const int m0   = blockIdx.y * 128;
    const int n0   = blockIdx.x * 128;
    const int moff = (wv & 1) * 64;
    const int noff = (wv >> 1) * 64;
    const int c15  = lane & 15;
    const int q    = lane >> 4;

    f32x4 acc[4][4];
#pragma unroll
    for (int i = 0; i < 4; i++)
#pragma unroll
        for (int j = 0; j < 4; j++) acc[i][j] = f32x4{0.f, 0.f, 0.f, 0.f};

    const int srow = tid >> 2;   // 0..63
    const int sc   = tid & 3;    // 8-elem chunk within 32-elem row

    for (int k0 = 0; k0 < HIDN; k0 += 32) {
#pragma unroll
        for (int i = 0; i < 2; i++) {
            int row = srow + i * 64;
            size_t arow = (idx != nullptr) ? (size_t)idx[m0 + row] : (size_t)(m0 + row);
            if constexpr (AFP32) {
                bf16x8 av = cvt8((const float*)Abase + arow * HIDN + k0 + sc * 8);
                *(bf16x8*)&At[row * 40 + sc * 8] = av;
            } else {
                uint4 av = *(const uint4*)((const __bf16*)Abase + arow * HIDN + k0 + sc * 8);
                *(uint4*)&At[row * 40 + sc * 8] = av;
            }
            int wrow = n0 + row; if (wrow >= N) wrow = N - 1;   // clamp; masked at store
            bf16x8 wv8 = cvt8(W + (size_t)wrow * wstride + k0 + sc * 8);
            *(bf16x8*)&Bt[row * 40 + sc * 8] = wv8;
        }
        __syncthreads();
        bf16x8 af[4], bfv[4];
#pragma unroll
        for (int mt = 0; mt < 4; mt++)
            af[mt] = *(const bf16x8*)&At[(moff + mt * 16 + c15) * 40 + q * 8];
#pragma unroll
        for (int nt = 0; nt < 4; nt++)
            bfv[nt] = *(const bf16x8*)&Bt[(noff + nt * 16 + c15) * 40 + q * 8];
#pragma unroll
        for (int mt = 0; mt < 4; mt++)
#pragma unroll
            for (int nt = 0; nt < 4; nt++)
                acc[mt][nt] = mfma16(af[mt], bfv[nt], acc[mt][nt]);
        __syncthreads();
    }

    float bv[4];
#pragma unroll
    for (int nt = 0; nt < 4; nt++) {
        int n = n0 + noff + nt * 16 + c15;
        bv[nt] = bias[n < N ? n : N - 1];
    }
#pragma unroll
    for (int mt = 0; mt < 4; mt++)
#pragma unroll
        for (int nt = 0; nt < 4; nt++) {
            int n = n0 + noff + nt * 16 + c15;
#pragma unroll
            for (int r = 0; r < 4; r++) {
                int m = m0 + moff + mt * 16 + q * 4 + r;
                if (n < N) outp[(size_t)m * ostride + n] = acc[mt][nt][r] + bv[nt];
            }
        }
}

// Sequential recurrence: 2 blocks x 16 batches, 8 waves; wave owns a 32-wide
// n-slice. W1h B-frags (bf16-converted) live in registers for the whole scan;
// h double-buffered in LDS (+8 row pad); pre prefetched 2 steps ahead.
// t-loop unrolled x2 so buffer index is compile-time.
__global__ __launch_bounds__(512, 1) void rnn_scan(
    const float* __restrict__ pre, const float* __restrict__ W1,
    __bf16* __restrict__ hs, float* __restrict__ hT)
{
    __shared__ __align__(16) __bf16 hbuf[2][16][264];
    const int tid  = threadIdx.x;
    const int lane = tid & 63;
    const int wv   = tid >> 6;        // 0..7
    const int b0   = blockIdx.x * 16;
    const int q    = lane >> 4;
    const int c15  = lane & 15;

    for (int i = tid; i < 2 * 16 * 264; i += 512) ((__bf16*)hbuf)[i] = (__bf16)0.0f;

    // B-frags: B[k][n] = W1[n][256+k],  n = wv*32 + nt*16 + c15
    bf16x8 bfrag[2][8];
#pragma unroll
    for (int nt = 0; nt < 2; nt++) {
        int n = wv * 32 + nt * 16 + c15;
        const float* base = W1 + (size_t)n * (2 * HIDN) + HIDN;
#pragma unroll
        for (int ks = 0; ks < 8; ks++)
            bfrag[nt][ks] = cvt8(base + ks * 32 + q * 8);
    }

    const float* pbase[8];
    __bf16*      hbase[8];
#pragma unroll
    for (int nt = 0; nt < 2; nt++)
#pragma unroll
        for (int r = 0; r < 4; r++) {
            int m = 4 * q + r;
            int n = wv * 32 + nt * 16 + c15;
            pbase[nt * 4 + r] = pre + (size_t)(b0 + m) * T_LEN * HIDN + n;
            hbase[nt * 4 + r] = hs  + (size_t)(b0 + m) * T_LEN * HIDN + n;
        }

    float pf[2][8];
#pragma unroll
    for (int i = 0; i < 8; i++) { pf[0][i] = pbase[i][0]; pf[1][i] = pbase[i][HIDN]; }

    __syncthreads();

    for (int t0 = 0; t0 < T_LEN; t0 += 2) {
#pragma unroll
        for (int half = 0; half < 2; half++) {
            const int t = t0 + half;
            const int cur = half;                 // compile-time buffer index
            float pv[8];
#pragma unroll
            for (int i = 0; i < 8; i++) pv[i] = pf[cur][i];
            if (t + 2 < T_LEN) {
#pragma unroll
                for (int i = 0; i < 8; i++) pf[cur][i] = pbase[i][(size_t)(t + 2) * HIDN];
            }

            bf16x8 af[8];
#pragma unroll
            for (int ks = 0; ks < 8; ks++)
                af[ks] = *(const bf16x8*)&hbuf[cur][c15][ks * 32 + q * 8];

            f32x4 a0 = f32x4{0.f, 0.f, 0.f, 0.f};
            f32x4 a1 = f32x4{0.f, 0.f, 0.f, 0.f};
#pragma unroll
            for (int ks = 0; ks < 8; ks++) {
                a0 = mfma16(af[ks], bfrag[0][ks], a0);
                a1 = mfma16(af[ks], bfrag[1][ks], a1);
            }

#pragma unroll
            for (int nt = 0; nt < 2; nt++) {
                f32x4 a = nt ? a1 : a0;
                int n = wv * 32 + nt * 16 + c15;
#pragma unroll
                for (int r = 0; r < 4; r++) {
                    float x  = a[r] + pv[nt * 4 + r];
                    float th = tanh_fast(x);
                    __bf16 hb = (__bf16)th;
                    hbuf[cur ^ 1][4 * q + r][n] = hb;          // next step's A operand
                    hbase[nt * 4 + r][(size_t)t * HIDN] = hb;  // hs for decode GEMM
                    if (t == T_LEN - 1)
                        hT[(size_t)(b0 + 4 * q + r) * HIDN + n] = th;  // fp32 tail state
                }
            }
            __syncthreads();
        }
    }
}

extern "C" void kernel_launch(void* const* d_in, const int* in_sizes, int n_in,
                              void* d_out, int out_size, void* d_ws, size_t ws_size,
                              hipStream_t stream)
{
    const int*   x   = (const int*)d_in[0];
    float*       emb = (float*)d_in[1];          // row 0 zeroed (padding_idx)
    const float* W1  = (const float*)d_in[2];    // [256][512]
    const float* b1  = (const float*)d_in[3];
    const float* Wd  = (const float*)d_in[4];    // [5000][256]
    const float* bd  = (const float*)d_in[5];
    float* out = (float*)d_out;

    // pre (fp32, 33.5MB) aliases the head of d_out: consumed by rnn_scan,
    // dead before the decode GEMM overwrites it. hs (bf16, 16.8MB) in ws.
    float*  pre = (float*)d_out;
    __bf16* hs  = (__bf16*)d_ws;

    zero_emb_row0<<<1, 256, 0, stream>>>(emb);
    // pre[b*T+t][j] = b1[j] + sum_k emb[x[b,t]][k] * W1[j][k]   (xt half of W1)
    gemm_bias<true><<<dim3(2, 256), 256, 0, stream>>>(
        (const void*)emb, x, W1, 2 * HIDN, b1, pre, HIDN, HIDN);
    rnn_scan<<<2, 512, 0, stream>>>(pre, W1, hs, out + OUT_ELEMS);
    // out[b*T+t][v] = bd[v] + sum_h hs[b*T+t][h] * Wd[v][h]
    gemm_bias<false><<<dim3(40, 256), 256, 0, stream>>>(
        (const void*)hs, nullptr, Wd, HIDN, bd, out, VOCAB, VOCAB);
}